// Round 5
// baseline (846.150 us; speedup 1.0000x reference)
//
#include <hip/hip_runtime.h>
#include <hip/hip_fp16.h>

#define B_ 32
#define T_ 336
#define NH 100
#define NM 150
#define FH 8
#define FM 16
#define HG 64
#define FUT 24
#define EH 300
#define EM 500

// ws layout in 4-byte elements. WRELH/WRELM/WROOT are contiguous => wcat[32][64]
#define WRELH 0       // rows 0-7   : 0.5*W_rel_h^T
#define WRELM 512     // rows 8-23  : 0.5*W_rel_m^T
#define WROOT 1536    // rows 24-31 : 0.5*(W_root_h+W_root_m)^T
#define BIASC 2048    // 64
#define OFFH  2112    // 101 ints
#define SRCH  2304    // 300 ints
#define OFFM  2624    // 101 ints
#define SRCM  2752    // 500 ints
#define XBUF_F 4096   // fp16 x buffer [G][NH][HG] (float-element offset)

typedef _Float16 half8 __attribute__((ext_vector_type(8)));
typedef float floatx4 __attribute__((ext_vector_type(4)));

#define XH_STRIDE 136   // fp16 elems per row of [x|h] LDS tile (272B)
#define GPB 2           // graphs per gnn block

__device__ __forceinline__ float fsigmoid(float x) {
    return __builtin_amdgcn_rcpf(1.0f + __expf(-x));
}
__device__ __forceinline__ float ftanh(float x) {
    return 1.0f - 2.0f * __builtin_amdgcn_rcpf(1.0f + __expf(2.0f * x));
}
__device__ __forceinline__ float lrelu(float x) { return x >= 0.0f ? x : 0.01f * x; }

// ---------------------------------------------------------------- prep ------
__global__ __launch_bounds__(256) void prep_kernel(
    const float* __restrict__ W_rel_m, const float* __restrict__ b_rel_m,
    const float* __restrict__ W_root_m, const float* __restrict__ W_rel_h,
    const float* __restrict__ b_rel_h, const float* __restrict__ W_root_h,
    const int* __restrict__ he, const int* __restrict__ me,
    float* __restrict__ ws)
{
    const int tid = threadIdx.x;
    int* wsI = (int*)ws;
    __shared__ int cnt[NH + 1];
    __shared__ int cur[NH + 1];

    for (int idx = tid; idx < HG * FH; idx += 256) {
        int j = idx >> 3, k = idx & 7;
        ws[WRELH + k * HG + j] = 0.5f * W_rel_h[j * FH + k];
        ws[WROOT + k * HG + j] = 0.5f * (W_root_h[j * FH + k] + W_root_m[j * FH + k]);
    }
    for (int idx = tid; idx < HG * FM; idx += 256) {
        int j = idx >> 4, k = idx & 15;
        ws[WRELM + k * HG + j] = 0.5f * W_rel_m[j * FM + k];
    }
    if (tid < HG) ws[BIASC + tid] = 0.5f * (b_rel_h[tid] + b_rel_m[tid]);

    // ---- hydro CSR (tgt -> list of src) ----
    if (tid <= NH) cnt[tid] = 0;
    __syncthreads();
    for (int e = tid; e < EH; e += 256) atomicAdd(&cnt[he[EH + e]], 1);
    __syncthreads();
    if (tid == 0) {
        int s = 0;
        for (int n2 = 0; n2 < NH; ++n2) { int c = cnt[n2]; cur[n2] = s; cnt[n2] = s; s += c; }
        cnt[NH] = s;
    }
    __syncthreads();
    if (tid <= NH) wsI[OFFH + tid] = cnt[tid];
    for (int e = tid; e < EH; e += 256) {
        int t = he[EH + e];
        int p = atomicAdd(&cur[t], 1);
        wsI[SRCH + p] = he[e];
    }
    __syncthreads();

    // ---- meteo CSR ----
    if (tid <= NH) cnt[tid] = 0;
    __syncthreads();
    for (int e = tid; e < EM; e += 256) atomicAdd(&cnt[me[EM + e]], 1);
    __syncthreads();
    if (tid == 0) {
        int s = 0;
        for (int n2 = 0; n2 < NH; ++n2) { int c = cnt[n2]; cur[n2] = s; cnt[n2] = s; s += c; }
        cnt[NH] = s;
    }
    __syncthreads();
    if (tid <= NH) wsI[OFFM + tid] = cnt[tid];
    for (int e = tid; e < EM; e += 256) {
        int t = me[EM + e];
        int p = atomicAdd(&cur[t], 1);
        wsI[SRCM + p] = me[e];
    }
}

// ---------------------------------------------------------------- GNN -------
// GPB graphs per block; per graph: stage x -> aggregate into vcat[100][36]
// (agg_h | agg_m | x_root) -> fp32 matmul with per-thread W column slice.
__global__ __launch_bounds__(256) void gnn_kernel(
    const float* __restrict__ dm, const float* __restrict__ dh,
    const float* __restrict__ ws, __half* __restrict__ xout)
{
    __shared__ __align__(16) float xh[NH * FH];      // 800
    __shared__ __align__(16) float xm[NM * FM];      // 2400
    __shared__ __align__(16) float vcat[NH * 36];    // 3600
    __shared__ __align__(16) float wcat[32 * 64];    // 2048
    __shared__ __align__(16) float biasc[HG];
    __shared__ int offh[NH + 1], offm[NH + 1];
    __shared__ int srch[EH], srcm[EM];

    const int tid = threadIdx.x;
    const int* wsI = (const int*)ws;

    // one-time staging (weights + edges)
    for (int i = tid; i < 2048 / 4; i += 256) ((float4*)wcat)[i] = ((const float4*)ws)[i];
    if (tid < HG) biasc[tid] = ws[BIASC + tid];
    for (int i = tid; i <= NH; i += 256) { offh[i] = wsI[OFFH + i]; offm[i] = wsI[OFFM + i]; }
    for (int i = tid; i < EH; i += 256) srch[i] = wsI[SRCH + i];
    for (int i = tid; i < EM; i += 256) srcm[i] = wsI[SRCM + i];

    const int r  = tid >> 4;          // node residue 0..15
    const int j0 = (tid & 15) << 2;   // output column slice
    const int cnt_n = (r < 4) ? 7 : 6;  // n = r + 16*i <= 99

#pragma unroll 1
    for (int gi = 0; gi < GPB; ++gi) {
        const int g = blockIdx.x * GPB + gi;
        {
            const float4* s = (const float4*)(dh + (size_t)g * (NH * FH));
            for (int i = tid; i < (NH * FH) / 4; i += 256) ((float4*)xh)[i] = s[i];
        }
        {
            const float4* s = (const float4*)(dm + (size_t)g * (NM * FM));
            for (int i = tid; i < (NM * FM) / 4; i += 256) ((float4*)xm)[i] = s[i];
        }
        __syncthreads();

        for (int s = tid; s < NH * FH; s += 256) {
            int nn = s >> 3, k = s & 7;
            float a = 0.f;
            for (int e = offh[nn]; e < offh[nn + 1]; ++e) a += xh[srch[e] * FH + k];
            vcat[nn * 36 + k] = a;
            vcat[nn * 36 + 24 + k] = xh[nn * FH + k];
        }
        for (int s = tid; s < NH * FM; s += 256) {
            int nn = s >> 4, k = s & 15;
            float a = 0.f;
            for (int e = offm[nn]; e < offm[nn + 1]; ++e) a += xm[srcm[e] * FM + k];
            vcat[nn * 36 + 8 + k] = a;
        }
        __syncthreads();

        // matmul: thread owns cols j0..j0+3 for nodes r+16*i
        float4 acc[7];
        const float4 bias4 = *(const float4*)&biasc[j0];
#pragma unroll
        for (int i = 0; i < 7; ++i) acc[i] = bias4;

#pragma unroll
        for (int k4 = 0; k4 < 8; ++k4) {
            float4 w0 = *(const float4*)&wcat[(4 * k4 + 0) * 64 + j0];
            float4 w1 = *(const float4*)&wcat[(4 * k4 + 1) * 64 + j0];
            float4 w2 = *(const float4*)&wcat[(4 * k4 + 2) * 64 + j0];
            float4 w3 = *(const float4*)&wcat[(4 * k4 + 3) * 64 + j0];
#pragma unroll
            for (int i = 0; i < 7; ++i) {
                if (i < cnt_n) {
                    int nn = r + 16 * i;
                    float4 va = *(const float4*)&vcat[nn * 36 + 4 * k4];
                    acc[i].x += va.x * w0.x + va.y * w1.x + va.z * w2.x + va.w * w3.x;
                    acc[i].y += va.x * w0.y + va.y * w1.y + va.z * w2.y + va.w * w3.y;
                    acc[i].z += va.x * w0.z + va.y * w1.z + va.z * w2.z + va.w * w3.z;
                    acc[i].w += va.x * w0.w + va.y * w1.w + va.z * w2.w + va.w * w3.w;
                }
            }
        }

        __half* xg = xout + (size_t)g * (NH * HG);
#pragma unroll
        for (int i = 0; i < 7; ++i) {
            if (i < cnt_n) {
                int nn = r + 16 * i;
                float ax = lrelu(acc[i].x), ay = lrelu(acc[i].y);
                float az = lrelu(acc[i].z), aw = lrelu(acc[i].w);
                __half2 lo = __halves2half2(__float2half_rn(ax), __float2half_rn(ay));
                __half2 hi = __halves2half2(__float2half_rn(az), __float2half_rn(aw));
                __half2* dst = (__half2*)(xg + nn * HG + j0);
                dst[0] = lo; dst[1] = hi;
            }
        }
        // no barrier needed: next-iter staging touches xh/xm only; the
        // post-staging barrier separates this iter's vcat reads from the
        // next aggregation's vcat writes.
    }
}

// ---------------------------------------------------------------- LSTM ------
// block = (node n, batch-half): 200 blocks x 256 threads (4 waves).
// Gate-column permutation: wave w, lane-col m16 -> unit u = 16w+m16; the 4
// accumulators of a thread are the 4 gates (i,f,g,o) of unit u for 4 batches
// => combine is fully in-register (no gates LDS round-trip). Double-buffered
// [x|h] tile => ONE barrier per timestep.
__global__ __launch_bounds__(256) void lstm_kernel(
    const __half* __restrict__ xbuf,
    const float* __restrict__ Wih, const float* __restrict__ Whh,
    const float* __restrict__ bih, const float* __restrict__ bhh,
    const float* __restrict__ Wlin, const float* __restrict__ blin,
    float* __restrict__ out)
{
    __shared__ __align__(16) _Float16 xh2[2][16 * XH_STRIDE];  // 2 x 4352 B
    __shared__ __align__(16) float hb32[16 * 68];              // fp32 h_T

    const int tid = threadIdx.x;
    const int n = blockIdx.x >> 1;
    const int half_ = blockIdx.x & 1;
    const int w = tid >> 6, l = tid & 63;
    const int m16 = l & 15, g4 = l >> 4;
    const int u = 16 * w + m16;             // owned hidden unit

    // ---- B-fragments: bf[g][kt] holds W[64g+u][k] slices (fp16) ----
    half8 bf[4][4];
    float biasr[4];
#pragma unroll
    for (int g = 0; g < 4; ++g) {
        const int gcol = 64 * g + u;
        const float* wi = Wih + ((size_t)n * 256 + gcol) * 64;
        const float* wh = Whh + ((size_t)n * 256 + gcol) * 64;
        biasr[g] = bih[n * 256 + gcol] + bhh[n * 256 + gcol];
#pragma unroll
        for (int kt = 0; kt < 4; ++kt) {
            const int kb = kt * 32 + g4 * 8;
            const float* src = (kb < 64) ? (wi + kb) : (wh + (kb - 64));
            float4 lo = *(const float4*)src;
            float4 hi = *(const float4*)(src + 4);
            half8 f;
            f[0] = (_Float16)lo.x; f[1] = (_Float16)lo.y;
            f[2] = (_Float16)lo.z; f[3] = (_Float16)lo.w;
            f[4] = (_Float16)hi.x; f[5] = (_Float16)hi.y;
            f[6] = (_Float16)hi.z; f[7] = (_Float16)hi.w;
            bf[g][kt] = f;
        }
    }

    // x staging: thread (pb, pk) loads 4 fp16 per step
    const unsigned short* xb_u = (const unsigned short*)xbuf;
    const int pb = tid >> 4;
    const int pk = (tid & 15) << 2;
    const size_t xrowbase = (size_t)(half_ * 16 + pb) * T_ * (NH * HG) + (size_t)n * HG + pk;

    // ---- prologue: x[0] -> buf0, h = 0 in buf0 ----
    {
        ushort4 x0 = *(const ushort4*)(xb_u + xrowbase);
        *(ushort4*)((unsigned short*)&xh2[0][0] + pb * XH_STRIDE + pk) = x0;
    }
    for (int i = tid; i < 16 * 64; i += 256)
        xh2[0][(i >> 6) * XH_STRIDE + 64 + (i & 63)] = (_Float16)0.f;
    __syncthreads();

    float cc[4] = {0.f, 0.f, 0.f, 0.f};
    int p = 0;

#pragma unroll 1
    for (int t = 0; t < T_; ++t) {
        const int tn = (t + 1 < T_) ? (t + 1) : (T_ - 1);
        ushort4 xpre = *(const ushort4*)(xb_u + xrowbase + (size_t)tn * (NH * HG));

        const _Float16* cb = &xh2[p][0];
        half8 af[4];
#pragma unroll
        for (int kt = 0; kt < 4; ++kt)
            af[kt] = *(const half8*)&cb[m16 * XH_STRIDE + kt * 32 + g4 * 8];

        floatx4 acc[4];
#pragma unroll
        for (int g = 0; g < 4; ++g) {
            float bg = biasr[g];
            floatx4 c = {bg, bg, bg, bg};
            acc[g] = c;
        }
#pragma unroll
        for (int kt = 0; kt < 4; ++kt) {
#pragma unroll
            for (int g = 0; g < 4; ++g)
                acc[g] = __builtin_amdgcn_mfma_f32_16x16x32_f16(af[kt], bf[g][kt], acc[g], 0, 0, 0);
        }

        // ---- in-register combine: thread owns unit u, batches 4*g4+r ----
        _Float16* nb = &xh2[p ^ 1][0];
#pragma unroll
        for (int r = 0; r < 4; ++r) {
            const int bb = 4 * g4 + r;
            float ai = acc[0][r], afv = acc[1][r], ag = acc[2][r], ao = acc[3][r];
            float c = fsigmoid(afv) * cc[r] + fsigmoid(ai) * ftanh(ag);
            cc[r] = c;
            float h = fsigmoid(ao) * ftanh(c);
            nb[bb * XH_STRIDE + 64 + u] = (_Float16)h;
            if (t == T_ - 1) hb32[bb * 68 + u] = h;
        }
        *(ushort4*)((unsigned short*)nb + pb * XH_STRIDE + pk) = xpre;

        __syncthreads();
        p ^= 1;
    }

    // ---- head: pred = leaky(h_T @ W_lin^T + b_lin) ----
    for (int task = tid; task < 16 * FUT; task += 256) {
        int b = task / FUT, j = task - b * FUT;
        float accv = blin[j];
        const float* wl = Wlin + j * 64;
        const float* hr = &hb32[b * 68];
#pragma unroll
        for (int k = 0; k < 64; k += 4) {
            float4 wv = *(const float4*)&wl[k];
            accv += wv.x * hr[k] + wv.y * hr[k + 1] + wv.z * hr[k + 2] + wv.w * hr[k + 3];
        }
        out[((size_t)(half_ * 16 + b) * NH + n) * FUT + j] = lrelu(accv);
    }
}

// ---------------------------------------------------------------- launch ----
extern "C" void kernel_launch(void* const* d_in, const int* in_sizes, int n_in,
                              void* d_out, int out_size, void* d_ws, size_t ws_size,
                              hipStream_t stream)
{
    const float* dm       = (const float*)d_in[0];
    const float* dh       = (const float*)d_in[1];
    const int*   he       = (const int*)d_in[2];
    const int*   me       = (const int*)d_in[3];
    const float* W_rel_m  = (const float*)d_in[4];
    const float* b_rel_m  = (const float*)d_in[5];
    const float* W_root_m = (const float*)d_in[6];
    const float* W_rel_h  = (const float*)d_in[7];
    const float* b_rel_h  = (const float*)d_in[8];
    const float* W_root_h = (const float*)d_in[9];
    const float* Wih      = (const float*)d_in[10];
    const float* Whh      = (const float*)d_in[11];
    const float* bih      = (const float*)d_in[12];
    const float* bhh      = (const float*)d_in[13];
    const float* Wlin     = (const float*)d_in[14];
    const float* blin     = (const float*)d_in[15];

    float* ws = (float*)d_ws;
    __half* xbuf = (__half*)(ws + XBUF_F);
    float* out = (float*)d_out;

    prep_kernel<<<1, 256, 0, stream>>>(W_rel_m, b_rel_m, W_root_m,
                                       W_rel_h, b_rel_h, W_root_h, he, me, ws);
    gnn_kernel<<<(B_ * T_) / GPB, 256, 0, stream>>>(dm, dh, ws, xbuf);
    lstm_kernel<<<NH * 2, 256, 0, stream>>>(xbuf, Wih, Whh, bih, bhh, Wlin, blin, out);
}